// Round 3
// baseline (975.687 us; speedup 1.0000x reference)
//
#include <hip/hip_runtime.h>
#include <cstdint>
#include <cstddef>

#define S_DIM 4096
#define B_DIM 32
#define H_DIM 512
#define M_DIM (S_DIM * B_DIM)

typedef unsigned short u16;
typedef unsigned int u32;
typedef float f32x4 __attribute__((ext_vector_type(4)));
typedef __bf16 bf16x8 __attribute__((ext_vector_type(8)));

__device__ __forceinline__ u16 f2bf(float v) {
    union { float f; u32 u; } a; a.f = v;
    u32 r = a.u + 0x7fffu + ((a.u >> 16) & 1u);   // RNE
    return (u16)(r >> 16);
}
__device__ __forceinline__ float bf2f(u16 b) {
    union { float f; u32 u; } a; a.u = ((u32)b) << 16; return a.f;
}
__device__ __forceinline__ void split_bf(float v, u16& h, u16& l) {
    h = f2bf(v);
    l = f2bf(v - bf2f(h));
}

// ---------------------------------------------------------------------------
// Kernel 1: split W (fp32 [H,H], row-major j,k) into bf16 hi/lo pair.
// ---------------------------------------------------------------------------
__global__ void prep_w(const float* __restrict__ W,
                       u16* __restrict__ Wh, u16* __restrict__ Wl) {
    int i = blockIdx.x * 256 + threadIdx.x;       // grid 1024 -> 262144 elems
    float w = W[i];
    u16 h, l;
    split_bf(w, h, l);
    Wh[i] = h; Wl[i] = l;
}

// ---------------------------------------------------------------------------
// Kernel 2: GEMM with full-K accumulation, epilogue hoisted out of K-loop.
//   Each block owns (mtile 128 rows) x (jtile 128 cols).
//   v[m,k] = enc[m,k] * hid[m%32, k]   (loaded+split in registers, no LDS)
//   acc    = sum over full K of v * W^T chunks (bf16x3 MFMA, fp32 accum)
//   Lp[jt][m] = sum_{j in jtile} encprev[m,j] * C[m,j]   (ONE epilogue/block)
// jt is the fastest-varying blockIdx component so the 4 sibling blocks that
// read the same enc rows dispatch adjacently (L3 temporal locality).
// No mid-loop barriers, no atomics; softmax sums the 4 jt partials.
// ---------------------------------------------------------------------------
__global__ __launch_bounds__(256, 2) void bigram_gemm(
    const float* __restrict__ enc,
    const float* __restrict__ hid,
    const u16* __restrict__ Wh,
    const u16* __restrict__ Wl,
    float* __restrict__ Lp)
{
    __shared__ float rowsum[2][128];

    const int tid  = threadIdx.x;
    const int wave = tid >> 6;
    const int lane = tid & 63;
    const int wr   = wave >> 1;                   // wave row (0..1) -> 64 rows
    const int wc   = wave & 1;                    // wave col (0..1) -> 64 cols
    const int jt   = blockIdx.x & 3;
    const int m0   = (blockIdx.x >> 2) * 128;
    const int j0   = jt * 128;

    const int g    = lane >> 4;                   // quad 0..3
    const int cl   = lane & 15;

    f32x4 acc[4][4];
    #pragma unroll
    for (int mf = 0; mf < 4; ++mf)
        #pragma unroll
        for (int nf = 0; nf < 4; ++nf)
            acc[mf][nf] = (f32x4){0.f, 0.f, 0.f, 0.f};

    for (int kt = 0; kt < 8; ++kt) {
        #pragma unroll
        for (int kk = 0; kk < 2; ++kk) {
            const int k0 = kt * 64 + kk * 32 + g * 8;
            // ---- A fragments: direct global load + multiply + split ----
            const float4 hA0 = *(const float4*)(hid + (size_t)cl * H_DIM + k0);
            const float4 hA1 = *(const float4*)(hid + (size_t)cl * H_DIM + k0 + 4);
            const float4 hB0 = *(const float4*)(hid + (size_t)(cl + 16) * H_DIM + k0);
            const float4 hB1 = *(const float4*)(hid + (size_t)(cl + 16) * H_DIM + k0 + 4);
            bf16x8 ah[4], al[4];
            #pragma unroll
            for (int mf = 0; mf < 4; ++mf) {
                const size_t rbase = (size_t)(m0 + wr * 64 + mf * 16 + cl) * H_DIM + k0;
                const float4 e0 = *(const float4*)(enc + rbase);
                const float4 e1 = *(const float4*)(enc + rbase + 4);
                const float4 h0 = (mf & 1) ? hB0 : hA0;
                const float4 h1 = (mf & 1) ? hB1 : hA1;
                float v[8];
                v[0] = e0.x * h0.x; v[1] = e0.y * h0.y; v[2] = e0.z * h0.z; v[3] = e0.w * h0.w;
                v[4] = e1.x * h1.x; v[5] = e1.y * h1.y; v[6] = e1.z * h1.z; v[7] = e1.w * h1.w;
                union { bf16x8 v8; u16 s[8]; } Hi, Lo;
                #pragma unroll
                for (int i = 0; i < 8; ++i) split_bf(v[i], Hi.s[i], Lo.s[i]);
                ah[mf] = Hi.v8;
                al[mf] = Lo.v8;
            }
            // ---- B fragments from pre-split W (L2-resident) ----
            bf16x8 bh[4], bl[4];
            #pragma unroll
            for (int nf = 0; nf < 4; ++nf) {
                const size_t roff = (size_t)(j0 + wc * 64 + nf * 16 + cl) * H_DIM + k0;
                bh[nf] = *(const bf16x8*)(Wh + roff);
                bl[nf] = *(const bf16x8*)(Wl + roff);
            }
            // ---- MFMA: bf16x3 split, acc accumulates over full K ----
            #pragma unroll
            for (int mf = 0; mf < 4; ++mf)
                #pragma unroll
                for (int nf = 0; nf < 4; ++nf) {
                    acc[mf][nf] = __builtin_amdgcn_mfma_f32_16x16x32_bf16(ah[mf], bh[nf], acc[mf][nf], 0, 0, 0);
                    acc[mf][nf] = __builtin_amdgcn_mfma_f32_16x16x32_bf16(ah[mf], bl[nf], acc[mf][nf], 0, 0, 0);
                    acc[mf][nf] = __builtin_amdgcn_mfma_f32_16x16x32_bf16(al[mf], bh[nf], acc[mf][nf], 0, 0, 0);
                }
        }
    }

    // ---- single epilogue: rowsum[row] = sum_col encprev[row-32, col] * C ----
    #pragma unroll
    for (int mf = 0; mf < 4; ++mf) {
        float rs0 = 0.f, rs1 = 0.f, rs2 = 0.f, rs3 = 0.f;
        const int growb = m0 + wr * 64 + mf * 16 + g * 4;
        #pragma unroll
        for (int nf = 0; nf < 4; ++nf) {
            const int gcol = j0 + wc * 64 + nf * 16 + cl;
            float e0 = (growb + 0 >= B_DIM) ? enc[(size_t)(growb + 0 - B_DIM) * H_DIM + gcol] : 0.f;
            float e1 = (growb + 1 >= B_DIM) ? enc[(size_t)(growb + 1 - B_DIM) * H_DIM + gcol] : 0.f;
            float e2 = (growb + 2 >= B_DIM) ? enc[(size_t)(growb + 2 - B_DIM) * H_DIM + gcol] : 0.f;
            float e3 = (growb + 3 >= B_DIM) ? enc[(size_t)(growb + 3 - B_DIM) * H_DIM + gcol] : 0.f;
            rs0 += acc[mf][nf][0] * e0;
            rs1 += acc[mf][nf][1] * e1;
            rs2 += acc[mf][nf][2] * e2;
            rs3 += acc[mf][nf][3] * e3;
        }
        #pragma unroll
        for (int off = 1; off < 16; off <<= 1) {
            rs0 += __shfl_xor(rs0, off);
            rs1 += __shfl_xor(rs1, off);
            rs2 += __shfl_xor(rs2, off);
            rs3 += __shfl_xor(rs3, off);
        }
        if (cl == 0) {
            const int rb = wr * 64 + mf * 16 + g * 4;   // disjoint across waves
            rowsum[wc][rb + 0] = rs0;
            rowsum[wc][rb + 1] = rs1;
            rowsum[wc][rb + 2] = rs2;
            rowsum[wc][rb + 3] = rs3;
        }
    }
    __syncthreads();
    if (tid < 128) {
        const int gm = m0 + tid;
        if (gm >= B_DIM) {
            // Lp[jt][b][s] with b = gm&31, s = gm>>5
            Lp[(size_t)jt * M_DIM + (size_t)(gm & 31) * S_DIM + (gm >> 5)] =
                rowsum[0][tid] + rowsum[1][tid];
        }
    }
}

// ---------------------------------------------------------------------------
// Kernel 3: per-b softmax over s, plus affect term and the s=0 logit.
// Lp holds 4 jt-partials, layout Lp[jt*M + b*S + s] (coalesced reads).
// ---------------------------------------------------------------------------
__global__ __launch_bounds__(1024) void softmax_kernel(
    const float* __restrict__ enc,
    const float* __restrict__ hid,
    const float* __restrict__ emb,
    const float* __restrict__ aff,
    const float* __restrict__ Lp,
    float* __restrict__ out)
{
    __shared__ float logits[S_DIM];
    __shared__ float wred[16][4];
    __shared__ float bcast[4];
    __shared__ float wtmp[16];

    const int b    = blockIdx.x;
    const int tid  = threadIdx.x;
    const int wave = tid >> 6;
    const int lane = tid & 63;

    // ha[k] = sum_h hid[b,h]*aff[h,k];  s0 = sum_h enc[0,b,h]*hid[b,h]
    float p0 = 0.f, p1 = 0.f, p2 = 0.f, p3 = 0.f;
    if (tid < H_DIM) {
        const int h = tid;
        const float hv = hid[b * H_DIM + h];
        p0 = hv * aff[h * 3 + 0];
        p1 = hv * aff[h * 3 + 1];
        p2 = hv * aff[h * 3 + 2];
        p3 = hv * enc[(size_t)b * H_DIM + h];
    }
    #pragma unroll
    for (int off = 32; off > 0; off >>= 1) {
        p0 += __shfl_down(p0, off);
        p1 += __shfl_down(p1, off);
        p2 += __shfl_down(p2, off);
        p3 += __shfl_down(p3, off);
    }
    if (lane == 0) { wred[wave][0] = p0; wred[wave][1] = p1; wred[wave][2] = p2; wred[wave][3] = p3; }
    __syncthreads();
    if (tid < 4) {
        float s = 0.f;
        #pragma unroll
        for (int w = 0; w < 16; ++w) s += wred[w][tid];
        bcast[tid] = s;
    }
    __syncthreads();
    const float ha0 = bcast[0], ha1 = bcast[1], ha2 = bcast[2], s0dot = bcast[3];

    float mx = -3.4e38f;
    #pragma unroll
    for (int it = 0; it < 4; ++it) {
        const int s = tid + it * 1024;
        const size_t base = (size_t)b * S_DIM + s;
        const float ed = (s == 0) ? s0dot
            : (Lp[base] + Lp[(size_t)M_DIM + base] + Lp[2 * (size_t)M_DIM + base] + Lp[3 * (size_t)M_DIM + base]);
        const float* e = emb + (size_t)(s * B_DIM + b) * 3;
        const float lg = ed + ha0 * e[0] + ha1 * e[1] + ha2 * e[2];
        logits[s] = lg;
        mx = fmaxf(mx, lg);
    }
    #pragma unroll
    for (int off = 32; off > 0; off >>= 1) mx = fmaxf(mx, __shfl_xor(mx, off));
    if (lane == 0) wtmp[wave] = mx;
    __syncthreads();
    mx = wtmp[0];
    #pragma unroll
    for (int w = 1; w < 16; ++w) mx = fmaxf(mx, wtmp[w]);
    __syncthreads();

    float sum = 0.f;
    #pragma unroll
    for (int it = 0; it < 4; ++it) {
        const int s = tid + it * 1024;
        const float ex = __expf(logits[s] - mx);
        logits[s] = ex;
        sum += ex;
    }
    #pragma unroll
    for (int off = 32; off > 0; off >>= 1) sum += __shfl_xor(sum, off);
    if (lane == 0) wtmp[wave] = sum;
    __syncthreads();
    sum = 0.f;
    #pragma unroll
    for (int w = 0; w < 16; ++w) sum += wtmp[w];
    const float inv = 1.0f / sum;
    #pragma unroll
    for (int it = 0; it < 4; ++it) {
        const int s = tid + it * 1024;
        out[(size_t)b * S_DIM + s] = logits[s] * inv;
    }
}

// ---------------------------------------------------------------------------
extern "C" void kernel_launch(void* const* d_in, const int* in_sizes, int n_in,
                              void* d_out, int out_size, void* d_ws, size_t ws_size,
                              hipStream_t stream) {
    const float* hid = (const float*)d_in[0];   // [1,B,H]
    const float* enc = (const float*)d_in[1];   // [S,B,H]
    const float* emb = (const float*)d_in[2];   // [S,B,3]
    const float* Wm  = (const float*)d_in[3];   // [H,H]
    const float* aff = (const float*)d_in[4];   // [H,3]
    float* out = (float*)d_out;                 // [B,1,S]

    char* ws = (char*)d_ws;
    u16*   Wh = (u16*)(ws);                     // 512 KB
    u16*   Wl = (u16*)(ws + (512u << 10));      // 512 KB
    float* Lp = (float*)(ws + (1024u << 10));   // 2 MB: Lp[4][B][S] jt-partials

    hipLaunchKernelGGL(prep_w,         dim3(1024), dim3(256),  0, stream, Wm, Wh, Wl);
    hipLaunchKernelGGL(bigram_gemm,    dim3(4096), dim3(256),  0, stream, enc, hid, Wh, Wl, Lp);
    hipLaunchKernelGGL(softmax_kernel, dim3(32),   dim3(1024), 0, stream, enc, hid, emb, aff, Lp, out);
}

// Round 4
// 646.017 us; speedup vs baseline: 1.5103x; 1.5103x over previous
//
#include <hip/hip_runtime.h>
#include <cstdint>
#include <cstddef>

#define S_DIM 4096
#define B_DIM 32
#define H_DIM 512
#define M_DIM (S_DIM * B_DIM)

typedef unsigned short u16;
typedef unsigned int u32;
typedef float f32x4 __attribute__((ext_vector_type(4)));
typedef __bf16 bf16x8 __attribute__((ext_vector_type(8)));

__device__ __forceinline__ u16 f2bf(float v) {
    union { float f; u32 u; } a; a.f = v;
    u32 r = a.u + 0x7fffu + ((a.u >> 16) & 1u);   // RNE
    return (u16)(r >> 16);
}
__device__ __forceinline__ float bf2f(u16 b) {
    union { float f; u32 u; } a; a.u = ((u32)b) << 16; return a.f;
}
__device__ __forceinline__ void split_bf(float v, u16& h, u16& l) {
    h = f2bf(v);
    l = f2bf(v - bf2f(h));
}

// async global->LDS, 16B per lane, dest = wave-uniform base + lane*16
__device__ __forceinline__ void gl2lds16(const void* g, void* l) {
    __builtin_amdgcn_global_load_lds(
        (const __attribute__((address_space(1))) unsigned int*)g,
        (__attribute__((address_space(3))) unsigned int*)l,
        16, 0, 0);
}

// ---------------------------------------------------------------------------
// Kernel 1: split W (fp32 [H,H] row-major j,k) into bf16 hi/lo pair.
// ---------------------------------------------------------------------------
__global__ void prep_w(const float* __restrict__ W,
                       u16* __restrict__ Wh, u16* __restrict__ Wl) {
    int i = blockIdx.x * 256 + threadIdx.x;       // grid 1024 -> 262144 elems
    float w = W[i];
    u16 h, l;
    split_bf(w, h, l);
    Wh[i] = h; Wl[i] = l;
}

// ---------------------------------------------------------------------------
// Kernel 1b: v[m,k] = enc[m,k] * hid[m&31, k], split into vh/vl bf16.
// Covers rows [m_base, m_base+m_count); vh/vl indexed relative to m_base.
// ---------------------------------------------------------------------------
__global__ void prep_v(const float* __restrict__ enc,
                       const float* __restrict__ hid,
                       u16* __restrict__ vh, u16* __restrict__ vl,
                       int m_base, int m_count) {
    const size_t nq = (size_t)m_count * (H_DIM / 4);      // float4 count
    const size_t stride = (size_t)gridDim.x * 256;
    for (size_t i = blockIdx.x * 256 + threadIdx.x; i < nq; i += stride) {
        const size_t elem  = i * 4;                        // local elem index
        const size_t gelem = (size_t)m_base * H_DIM + elem;
        const int k = (int)(gelem & (H_DIM - 1));
        const int b = (int)((gelem >> 9) & 31);
        const float4 e = *(const float4*)(enc + gelem);
        const float4 h = *(const float4*)(hid + b * H_DIM + k);
        float v0 = e.x * h.x, v1 = e.y * h.y, v2 = e.z * h.z, v3 = e.w * h.w;
        u16 h0,h1,h2,h3,l0,l1,l2,l3;
        split_bf(v0, h0, l0); split_bf(v1, h1, l1);
        split_bf(v2, h2, l2); split_bf(v3, h3, l3);
        ushort4 hw, lw;
        hw.x = h0; hw.y = h1; hw.z = h2; hw.w = h3;
        lw.x = l0; lw.y = l1; lw.z = l2; lw.w = l3;
        *(ushort4*)(vh + elem) = hw;
        *(ushort4*)(vl + elem) = lw;
    }
}

// ---------------------------------------------------------------------------
// Kernel 2: pure-bf16 m97-style GEMM + one epilogue per block.
//   C[m,j] = sum_k v[m,k] * W[j,k]    (bf16x3 MFMA, fp32 accum)
//   Lp[jt][m] = sum_{j in jtile} enc[m-32, j] * C[m,j]
// 128x128 tile, BK=32, 4 LDS buffers staged via global_load_lds width=16,
// 2-barrier K-loop, no VALU in the operand path.
// ---------------------------------------------------------------------------
__global__ __launch_bounds__(256, 2) void bigram_gemm(
    const float* __restrict__ enc,
    const u16* __restrict__ vh, const u16* __restrict__ vl,
    const u16* __restrict__ Wh, const u16* __restrict__ Wl,
    float* __restrict__ Lp, int m_base)
{
    __shared__ u16 sAh[128 * 32];
    __shared__ u16 sAl[128 * 32];
    __shared__ u16 sBh[128 * 32];
    __shared__ u16 sBl[128 * 32];
    __shared__ float rowsum[2][128];

    const int tid  = threadIdx.x;
    const int wave = tid >> 6;
    const int lane = tid & 63;
    const int wr   = wave >> 1;                   // wave row (0..1)
    const int wc   = wave & 1;                    // wave col (0..1)
    const int jt   = blockIdx.x & 3;
    const int mt   = blockIdx.x >> 2;
    const int m0   = m_base + mt * 128;           // absolute m of tile row 0
    const int j0   = jt * 128;
    const int g    = lane >> 4;                   // quad 0..3
    const int cl   = lane & 15;

    // staging geometry: two 1KB segments per wave per buffer.
    // seg = wave*2+q covers rows seg*16..seg*16+15; lane -> (row=lane>>2, col=(lane&3)*8)
    const int srow = wave * 32 + (lane >> 2);     // seg0 row for this lane
    const int scol = (lane & 3) * 8;
    const size_t aoff0 = (size_t)(mt * 128 + srow) * H_DIM + scol;   // local v rows
    const size_t aoff1 = aoff0 + (size_t)16 * H_DIM;
    const size_t boff0 = (size_t)(j0 + srow) * H_DIM + scol;
    const size_t boff1 = boff0 + (size_t)16 * H_DIM;
    const u16* pAh0 = vh + aoff0; const u16* pAh1 = vh + aoff1;
    const u16* pAl0 = vl + aoff0; const u16* pAl1 = vl + aoff1;
    const u16* pBh0 = Wh + boff0; const u16* pBh1 = Wh + boff1;
    const u16* pBl0 = Wl + boff0; const u16* pBl1 = Wl + boff1;
    // wave-uniform LDS dests (shorts): seg0 = wave*1024, seg1 = +512
    const int d0 = wave * 1024, d1 = wave * 1024 + 512;

    f32x4 acc[4][4];
    #pragma unroll
    for (int mf = 0; mf < 4; ++mf)
        #pragma unroll
        for (int nf = 0; nf < 4; ++nf)
            acc[mf][nf] = (f32x4){0.f, 0.f, 0.f, 0.f};

    for (int kt = 0; kt < 16; ++kt) {
        const int ko = kt * 32;                   // shorts
        __syncthreads();
        gl2lds16(pAh0 + ko, sAh + d0);
        gl2lds16(pAh1 + ko, sAh + d1);
        gl2lds16(pAl0 + ko, sAl + d0);
        gl2lds16(pAl1 + ko, sAl + d1);
        gl2lds16(pBh0 + ko, sBh + d0);
        gl2lds16(pBh1 + ko, sBh + d1);
        gl2lds16(pBl0 + ko, sBl + d0);
        gl2lds16(pBl1 + ko, sBl + d1);
        __syncthreads();

        bf16x8 ah[4], al[4], bh[4], bl[4];
        #pragma unroll
        for (int mf = 0; mf < 4; ++mf) {
            const int ar = wr * 64 + mf * 16 + cl;
            ah[mf] = *(const bf16x8*)(sAh + ar * 32 + g * 8);
            al[mf] = *(const bf16x8*)(sAl + ar * 32 + g * 8);
        }
        #pragma unroll
        for (int nf = 0; nf < 4; ++nf) {
            const int br = wc * 64 + nf * 16 + cl;
            bh[nf] = *(const bf16x8*)(sBh + br * 32 + g * 8);
            bl[nf] = *(const bf16x8*)(sBl + br * 32 + g * 8);
        }
        #pragma unroll
        for (int mf = 0; mf < 4; ++mf)
            #pragma unroll
            for (int nf = 0; nf < 4; ++nf) {
                acc[mf][nf] = __builtin_amdgcn_mfma_f32_16x16x32_bf16(ah[mf], bh[nf], acc[mf][nf], 0, 0, 0);
                acc[mf][nf] = __builtin_amdgcn_mfma_f32_16x16x32_bf16(ah[mf], bl[nf], acc[mf][nf], 0, 0, 0);
                acc[mf][nf] = __builtin_amdgcn_mfma_f32_16x16x32_bf16(al[mf], bh[nf], acc[mf][nf], 0, 0, 0);
            }
    }

    // ---- single epilogue: rowsum[row] = sum_col enc[row-32, col] * C ----
    #pragma unroll
    for (int mf = 0; mf < 4; ++mf) {
        float rs0 = 0.f, rs1 = 0.f, rs2 = 0.f, rs3 = 0.f;
        const int growb = m0 + wr * 64 + mf * 16 + g * 4;
        #pragma unroll
        for (int nf = 0; nf < 4; ++nf) {
            const int gcol = j0 + wc * 64 + nf * 16 + cl;
            float e0 = (growb + 0 >= B_DIM) ? enc[(size_t)(growb + 0 - B_DIM) * H_DIM + gcol] : 0.f;
            float e1 = (growb + 1 >= B_DIM) ? enc[(size_t)(growb + 1 - B_DIM) * H_DIM + gcol] : 0.f;
            float e2 = (growb + 2 >= B_DIM) ? enc[(size_t)(growb + 2 - B_DIM) * H_DIM + gcol] : 0.f;
            float e3 = (growb + 3 >= B_DIM) ? enc[(size_t)(growb + 3 - B_DIM) * H_DIM + gcol] : 0.f;
            rs0 += acc[mf][nf][0] * e0;
            rs1 += acc[mf][nf][1] * e1;
            rs2 += acc[mf][nf][2] * e2;
            rs3 += acc[mf][nf][3] * e3;
        }
        #pragma unroll
        for (int off = 1; off < 16; off <<= 1) {
            rs0 += __shfl_xor(rs0, off);
            rs1 += __shfl_xor(rs1, off);
            rs2 += __shfl_xor(rs2, off);
            rs3 += __shfl_xor(rs3, off);
        }
        if (cl == 0) {
            const int rb = wr * 64 + mf * 16 + g * 4;   // disjoint across waves
            rowsum[wc][rb + 0] = rs0;
            rowsum[wc][rb + 1] = rs1;
            rowsum[wc][rb + 2] = rs2;
            rowsum[wc][rb + 3] = rs3;
        }
    }
    __syncthreads();
    if (tid < 128) {
        const int gm = m0 + tid;
        if (gm >= B_DIM) {
            Lp[(size_t)jt * M_DIM + (size_t)(gm & 31) * S_DIM + (gm >> 5)] =
                rowsum[0][tid] + rowsum[1][tid];
        }
    }
}

// ---------------------------------------------------------------------------
// Fallback GEMM (R3 structure, no workspace for vh/vl needed) — used only if
// ws_size is too small to hold even one 128-row chunk of vh/vl.
// ---------------------------------------------------------------------------
__global__ __launch_bounds__(256, 2) void bigram_gemm_direct(
    const float* __restrict__ enc,
    const float* __restrict__ hid,
    const u16* __restrict__ Wh,
    const u16* __restrict__ Wl,
    float* __restrict__ Lp)
{
    __shared__ float rowsum[2][128];
    const int tid  = threadIdx.x;
    const int wave = tid >> 6;
    const int lane = tid & 63;
    const int wr   = wave >> 1;
    const int wc   = wave & 1;
    const int jt   = blockIdx.x & 3;
    const int m0   = (blockIdx.x >> 2) * 128;
    const int j0   = jt * 128;
    const int g    = lane >> 4;
    const int cl   = lane & 15;

    f32x4 acc[4][4];
    #pragma unroll
    for (int mf = 0; mf < 4; ++mf)
        #pragma unroll
        for (int nf = 0; nf < 4; ++nf)
            acc[mf][nf] = (f32x4){0.f, 0.f, 0.f, 0.f};

    for (int kt = 0; kt < 8; ++kt) {
        #pragma unroll
        for (int kk = 0; kk < 2; ++kk) {
            const int k0 = kt * 64 + kk * 32 + g * 8;
            const float4 hA0 = *(const float4*)(hid + (size_t)cl * H_DIM + k0);
            const float4 hA1 = *(const float4*)(hid + (size_t)cl * H_DIM + k0 + 4);
            const float4 hB0 = *(const float4*)(hid + (size_t)(cl + 16) * H_DIM + k0);
            const float4 hB1 = *(const float4*)(hid + (size_t)(cl + 16) * H_DIM + k0 + 4);
            bf16x8 ah[4], al[4];
            #pragma unroll
            for (int mf = 0; mf < 4; ++mf) {
                const size_t rbase = (size_t)(m0 + wr * 64 + mf * 16 + cl) * H_DIM + k0;
                const float4 e0 = *(const float4*)(enc + rbase);
                const float4 e1 = *(const float4*)(enc + rbase + 4);
                const float4 h0 = (mf & 1) ? hB0 : hA0;
                const float4 h1 = (mf & 1) ? hB1 : hA1;
                float v[8];
                v[0] = e0.x * h0.x; v[1] = e0.y * h0.y; v[2] = e0.z * h0.z; v[3] = e0.w * h0.w;
                v[4] = e1.x * h1.x; v[5] = e1.y * h1.y; v[6] = e1.z * h1.z; v[7] = e1.w * h1.w;
                union { bf16x8 v8; u16 s[8]; } Hi, Lo;
                #pragma unroll
                for (int i = 0; i < 8; ++i) split_bf(v[i], Hi.s[i], Lo.s[i]);
                ah[mf] = Hi.v8;
                al[mf] = Lo.v8;
            }
            bf16x8 bh[4], bl[4];
            #pragma unroll
            for (int nf = 0; nf < 4; ++nf) {
                const size_t roff = (size_t)(j0 + wc * 64 + nf * 16 + cl) * H_DIM + k0;
                bh[nf] = *(const bf16x8*)(Wh + roff);
                bl[nf] = *(const bf16x8*)(Wl + roff);
            }
            #pragma unroll
            for (int mf = 0; mf < 4; ++mf)
                #pragma unroll
                for (int nf = 0; nf < 4; ++nf) {
                    acc[mf][nf] = __builtin_amdgcn_mfma_f32_16x16x32_bf16(ah[mf], bh[nf], acc[mf][nf], 0, 0, 0);
                    acc[mf][nf] = __builtin_amdgcn_mfma_f32_16x16x32_bf16(ah[mf], bl[nf], acc[mf][nf], 0, 0, 0);
                    acc[mf][nf] = __builtin_amdgcn_mfma_f32_16x16x32_bf16(al[mf], bh[nf], acc[mf][nf], 0, 0, 0);
                }
        }
    }

    #pragma unroll
    for (int mf = 0; mf < 4; ++mf) {
        float rs0 = 0.f, rs1 = 0.f, rs2 = 0.f, rs3 = 0.f;
        const int growb = m0 + wr * 64 + mf * 16 + g * 4;
        #pragma unroll
        for (int nf = 0; nf < 4; ++nf) {
            const int gcol = j0 + wc * 64 + nf * 16 + cl;
            float e0 = (growb + 0 >= B_DIM) ? enc[(size_t)(growb + 0 - B_DIM) * H_DIM + gcol] : 0.f;
            float e1 = (growb + 1 >= B_DIM) ? enc[(size_t)(growb + 1 - B_DIM) * H_DIM + gcol] : 0.f;
            float e2 = (growb + 2 >= B_DIM) ? enc[(size_t)(growb + 2 - B_DIM) * H_DIM + gcol] : 0.f;
            float e3 = (growb + 3 >= B_DIM) ? enc[(size_t)(growb + 3 - B_DIM) * H_DIM + gcol] : 0.f;
            rs0 += acc[mf][nf][0] * e0;
            rs1 += acc[mf][nf][1] * e1;
            rs2 += acc[mf][nf][2] * e2;
            rs3 += acc[mf][nf][3] * e3;
        }
        #pragma unroll
        for (int off = 1; off < 16; off <<= 1) {
            rs0 += __shfl_xor(rs0, off);
            rs1 += __shfl_xor(rs1, off);
            rs2 += __shfl_xor(rs2, off);
            rs3 += __shfl_xor(rs3, off);
        }
        if (cl == 0) {
            const int rb = wr * 64 + mf * 16 + g * 4;
            rowsum[wc][rb + 0] = rs0;
            rowsum[wc][rb + 1] = rs1;
            rowsum[wc][rb + 2] = rs2;
            rowsum[wc][rb + 3] = rs3;
        }
    }
    __syncthreads();
    if (tid < 128) {
        const int gm = m0 + tid;
        if (gm >= B_DIM) {
            Lp[(size_t)jt * M_DIM + (size_t)(gm & 31) * S_DIM + (gm >> 5)] =
                rowsum[0][tid] + rowsum[1][tid];
        }
    }
}

// ---------------------------------------------------------------------------
// Kernel 3: per-b softmax over s, plus affect term and the s=0 logit.
// ---------------------------------------------------------------------------
__global__ __launch_bounds__(1024) void softmax_kernel(
    const float* __restrict__ enc,
    const float* __restrict__ hid,
    const float* __restrict__ emb,
    const float* __restrict__ aff,
    const float* __restrict__ Lp,
    float* __restrict__ out)
{
    __shared__ float logits[S_DIM];
    __shared__ float wred[16][4];
    __shared__ float bcast[4];
    __shared__ float wtmp[16];

    const int b    = blockIdx.x;
    const int tid  = threadIdx.x;
    const int wave = tid >> 6;
    const int lane = tid & 63;

    float p0 = 0.f, p1 = 0.f, p2 = 0.f, p3 = 0.f;
    if (tid < H_DIM) {
        const int h = tid;
        const float hv = hid[b * H_DIM + h];
        p0 = hv * aff[h * 3 + 0];
        p1 = hv * aff[h * 3 + 1];
        p2 = hv * aff[h * 3 + 2];
        p3 = hv * enc[(size_t)b * H_DIM + h];
    }
    #pragma unroll
    for (int off = 32; off > 0; off >>= 1) {
        p0 += __shfl_down(p0, off);
        p1 += __shfl_down(p1, off);
        p2 += __shfl_down(p2, off);
        p3 += __shfl_down(p3, off);
    }
    if (lane == 0) { wred[wave][0] = p0; wred[wave][1] = p1; wred[wave][2] = p2; wred[wave][3] = p3; }
    __syncthreads();
    if (tid < 4) {
        float s = 0.f;
        #pragma unroll
        for (int w = 0; w < 16; ++w) s += wred[w][tid];
        bcast[tid] = s;
    }
    __syncthreads();
    const float ha0 = bcast[0], ha1 = bcast[1], ha2 = bcast[2], s0dot = bcast[3];

    float mx = -3.4e38f;
    #pragma unroll
    for (int it = 0; it < 4; ++it) {
        const int s = tid + it * 1024;
        const size_t base = (size_t)b * S_DIM + s;
        const float ed = (s == 0) ? s0dot
            : (Lp[base] + Lp[(size_t)M_DIM + base] + Lp[2 * (size_t)M_DIM + base] + Lp[3 * (size_t)M_DIM + base]);
        const float* e = emb + (size_t)(s * B_DIM + b) * 3;
        const float lg = ed + ha0 * e[0] + ha1 * e[1] + ha2 * e[2];
        logits[s] = lg;
        mx = fmaxf(mx, lg);
    }
    #pragma unroll
    for (int off = 32; off > 0; off >>= 1) mx = fmaxf(mx, __shfl_xor(mx, off));
    if (lane == 0) wtmp[wave] = mx;
    __syncthreads();
    mx = wtmp[0];
    #pragma unroll
    for (int w = 1; w < 16; ++w) mx = fmaxf(mx, wtmp[w]);
    __syncthreads();

    float sum = 0.f;
    #pragma unroll
    for (int it = 0; it < 4; ++it) {
        const int s = tid + it * 1024;
        const float ex = __expf(logits[s] - mx);
        logits[s] = ex;
        sum += ex;
    }
    #pragma unroll
    for (int off = 32; off > 0; off >>= 1) sum += __shfl_xor(sum, off);
    if (lane == 0) wtmp[wave] = sum;
    __syncthreads();
    sum = 0.f;
    #pragma unroll
    for (int w = 0; w < 16; ++w) sum += wtmp[w];
    const float inv = 1.0f / sum;
    #pragma unroll
    for (int it = 0; it < 4; ++it) {
        const int s = tid + it * 1024;
        out[(size_t)b * S_DIM + s] = logits[s] * inv;
    }
}

// ---------------------------------------------------------------------------
extern "C" void kernel_launch(void* const* d_in, const int* in_sizes, int n_in,
                              void* d_out, int out_size, void* d_ws, size_t ws_size,
                              hipStream_t stream) {
    const float* hid = (const float*)d_in[0];   // [1,B,H]
    const float* enc = (const float*)d_in[1];   // [S,B,H]
    const float* emb = (const float*)d_in[2];   // [S,B,3]
    const float* Wm  = (const float*)d_in[3];   // [H,H]
    const float* aff = (const float*)d_in[4];   // [H,3]
    float* out = (float*)d_out;                 // [B,1,S]

    char* ws = (char*)d_ws;
    u16*   Wh = (u16*)ws;                                   // 512 KB
    u16*   Wl = (u16*)(ws + (512u << 10));                  // 512 KB
    float* Lp = (float*)(ws + (1024u << 10));               // 2 MB: Lp[4][B][S]
    char*  vbase = ws + (1024u << 10) + (size_t)4 * M_DIM * 4;
    const size_t fixed = (1024u << 10) + (size_t)4 * M_DIM * 4;   // 3 MB

    hipLaunchKernelGGL(prep_w, dim3(1024), dim3(256), 0, stream, Wm, Wh, Wl);

    // how many 128-row chunks of vh/vl fit in the remaining workspace?
    const size_t avail = (ws_size > fixed) ? ws_size - fixed : 0;
    long chunk_m = (long)((avail / 2048) / 128) * 128;      // 2048 B per m-row (vh+vl)
    if (chunk_m > M_DIM) chunk_m = M_DIM;

    if (chunk_m >= 128) {
        u16* vh = (u16*)vbase;
        u16* vl = (u16*)(vbase + (size_t)chunk_m * H_DIM * sizeof(u16));
        for (long m_base = 0; m_base < M_DIM; m_base += chunk_m) {
            long mc = M_DIM - m_base;
            if (mc > chunk_m) mc = chunk_m;
            hipLaunchKernelGGL(prep_v, dim3((u32)(mc / 16)), dim3(256), 0, stream,
                               enc, hid, vh, vl, (int)m_base, (int)mc);
            hipLaunchKernelGGL(bigram_gemm, dim3((u32)((mc / 128) * 4)), dim3(256), 0, stream,
                               enc, vh, vl, Wh, Wl, Lp, (int)m_base);
        }
    } else {
        hipLaunchKernelGGL(bigram_gemm_direct, dim3(4096), dim3(256), 0, stream,
                           enc, hid, Wh, Wl, Lp);
    }

    hipLaunchKernelGGL(softmax_kernel, dim3(32), dim3(1024), 0, stream,
                       enc, hid, emb, aff, Lp, out);
}